// Round 8
// baseline (507.918 us; speedup 1.0000x reference)
//
#include <hip/hip_runtime.h>
#include <math.h>

#define CDIV(a,b) (((a)+(b)-1)/(b))

typedef __bf16 bf16x8 __attribute__((ext_vector_type(8)));
typedef float  f32x4  __attribute__((ext_vector_type(4)));
typedef __attribute__((address_space(3))) uint32_t lds_u32_t;
typedef __attribute__((address_space(1))) uint32_t glb_u32_t;

__device__ __forceinline__ float lrelu(float v){ return fmaxf(v, 0.2f*v); }

// ---------------- CSR build (by dst) ----------------
__global__ void k_count_deg(const int* __restrict__ edst, int E, int ET, int* __restrict__ off){
  int e = blockIdx.x*blockDim.x + threadIdx.x;
  if (e >= ET) return;
  int d = (e < E) ? edst[e] : (e - E);   // self-loops appended at the end
  atomicAdd(&off[d+1], 1);
}

__global__ __launch_bounds__(256) void k_scan_a(int* __restrict__ cnt, int n, int* __restrict__ bsum){
  int i = blockIdx.x*256 + threadIdx.x;
  int lane = threadIdx.x & 63, wv = threadIdx.x >> 6;
  int x = (i < n) ? cnt[i] : 0;
  #pragma unroll
  for (int d=1; d<64; d<<=1){ int y = __shfl_up(x, d, 64); if (lane >= d) x += y; }
  __shared__ int wsum[4];
  if (lane == 63) wsum[wv] = x;
  __syncthreads();
  #pragma unroll
  for (int j=0;j<3;j++) if (wv > j) x += wsum[j];
  if (i < n) cnt[i] = x;
  if (threadIdx.x == 255) bsum[blockIdx.x] = x;
}

__global__ __launch_bounds__(256) void k_scan_b(int* __restrict__ bsum, int nb){
  int t = threadIdx.x;
  int lane = t & 63, wv = t >> 6;
  int v = (t < nb) ? bsum[t] : 0;
  int x = v;
  #pragma unroll
  for (int d=1; d<64; d<<=1){ int y = __shfl_up(x, d, 64); if (lane >= d) x += y; }
  __shared__ int wsum[4];
  if (lane == 63) wsum[wv] = x;
  __syncthreads();
  #pragma unroll
  for (int j=0;j<3;j++) if (wv > j) x += wsum[j];
  if (t < nb) bsum[t] = x - v;   // exclusive
}

__global__ __launch_bounds__(256) void k_scan_c(int* __restrict__ off, int* __restrict__ cursor,
                                                const int* __restrict__ bsum, int n){
  int i = blockIdx.x*256 + threadIdx.x;
  if (i >= n) return;
  int v = off[1+i] + bsum[blockIdx.x];
  off[1+i] = v;
  if (i+1 < n) cursor[i+1] = v;
  if (i == 0) cursor[0] = 0;
}

__global__ void k_fill(const int* __restrict__ edst, int E, int ET,
                       int* __restrict__ cursor, int* __restrict__ adj){
  int e = blockIdx.x*blockDim.x + threadIdx.x;
  if (e >= ET) return;
  int d = (e < E) ? edst[e] : (e - E);
  int pos = atomicAdd(&cursor[d], 1);
  adj[pos] = e;
}

// ---------------- prep: fp32 -> bf16 convert ----------------
__global__ void k_cvt_bf16(const float* __restrict__ in, __bf16* __restrict__ out, int n4){
  int i = blockIdx.x*blockDim.x + threadIdx.x;
  if (i >= n4) return;
  float4 v = reinterpret_cast<const float4*>(in)[i];
  __bf16 o[4] = {(__bf16)v.x,(__bf16)v.y,(__bf16)v.z,(__bf16)v.w};
  *reinterpret_cast<ushort4*>(out + (size_t)i*4) =
      *reinterpret_cast<ushort4*>(o);
}

// ---------------- prep: Wt[c][k] = concat(Wl,Wr)[k][c] as bf16 ----------------
__global__ void k_prep_wt(const float* __restrict__ Wl, const float* __restrict__ Wr,
                          __bf16* __restrict__ Wt, int K, int Nh){
  int c = blockIdx.x, k = threadIdx.x;
  float v = (c < Nh) ? Wl[(size_t)k*Nh + c] : Wr[(size_t)k*Nh + (c - Nh)];
  Wt[(size_t)c*K + k] = (__bf16)v;
}

// ---------------- bf16 MFMA GEMM, m97-style ----------------
__global__ __launch_bounds__(256) void gemm_mfma(
    const __bf16* __restrict__ A, int M, int K,
    const __bf16* __restrict__ Bt, int N,
    __bf16* __restrict__ C)
{
  __shared__ __bf16 As[2][128*32];
  __shared__ __bf16 Bs[2][128*32];
  int tid = threadIdx.x;
  int w = tid >> 6, lane = tid & 63;
  int g = lane >> 4, r16 = lane & 15;
  int wr = w >> 1, wc = w & 1;
  int row0 = blockIdx.x * 128;
  int col0 = blockIdx.y * 128;
  int srow = tid >> 2, sslot = tid & 3;

  auto f = [](int r){ return (r + (r >> 2)) & 3; };

  f32x4 acc[4][4];
  #pragma unroll
  for (int m=0;m<4;m++)
    #pragma unroll
    for (int n=0;n<4;n++) acc[m][n] = (f32x4){0.f,0.f,0.f,0.f};

  auto STAGE = [&](int buf, int kt){
    #pragma unroll
    for (int i=0;i<2;i++){
      int trow = i*64 + srow;
      int arow = row0 + trow; if (arow >= M) arow = M-1;
      const __bf16* ga = A + (size_t)arow*K + kt*32 + ((sslot ^ f(trow))<<3);
      __builtin_amdgcn_global_load_lds((const glb_u32_t*)(const void*)ga,
          (lds_u32_t*)(void*)&As[buf][(i*64 + w*16)*32], 16, 0, 0);
      const __bf16* gb = Bt + (size_t)(col0 + trow)*K + kt*32 + ((sslot ^ f(trow))<<3);
      __builtin_amdgcn_global_load_lds((const glb_u32_t*)(const void*)gb,
          (lds_u32_t*)(void*)&Bs[buf][(i*64 + w*16)*32], 16, 0, 0);
    }
  };

  int nk = K >> 5;
  STAGE(0, 0);
  for (int kt = 0; kt < nk; ++kt){
    int cur = kt & 1;
    __syncthreads();
    if (kt+1 < nk) STAGE(cur^1, kt+1);
    bf16x8 a[4], b[4];
    #pragma unroll
    for (int m=0;m<4;m++){
      int row = wr*64 + m*16 + r16;
      a[m] = *reinterpret_cast<const bf16x8*>(&As[cur][row*32 + ((g ^ f(row))<<3)]);
    }
    #pragma unroll
    for (int n=0;n<4;n++){
      int row = wc*64 + n*16 + r16;
      b[n] = *reinterpret_cast<const bf16x8*>(&Bs[cur][row*32 + ((g ^ f(row))<<3)]);
    }
    #pragma unroll
    for (int m=0;m<4;m++)
      #pragma unroll
      for (int n=0;n<4;n++)
        acc[m][n] = __builtin_amdgcn_mfma_f32_16x16x32_bf16(a[m], b[n], acc[m][n], 0, 0, 0);
  }

  #pragma unroll
  for (int m=0;m<4;m++){
    int row_c = row0 + wr*64 + m*16 + g*4;
    #pragma unroll
    for (int n=0;n<4;n++){
      int col_c = col0 + wc*64 + n*16 + r16;
      #pragma unroll
      for (int r=0;r<4;r++)
        if (row_c + r < M) C[(size_t)(row_c+r)*N + col_c] = (__bf16)acc[m][n][r];
    }
  }
}

// ---------------- layer 1 fused v4: 1 wave/node, 32-edge batched gather ------
// lane = h*8 + e. Batch = 4 chunks of 8 edges: all adj loads issued flat, then
// all esrc, then all 8 row-halves -> 3 latency epochs per 32 edges instead of
// 3 per 8. Softmax max/rescale once per batch. Typical deg (~17) = 1 batch.
__global__ __launch_bounds__(256) void k_fused1(
    const int* __restrict__ off, const int* __restrict__ adj,
    const int* __restrict__ esrc, int E, int N,
    const __bf16* __restrict__ H1, const float* __restrict__ att1,
    const float* __restrict__ b1, __bf16* __restrict__ out1)
{
  __shared__ float obuf[4][128];
  int wid = threadIdx.x >> 6;
  int node = blockIdx.x*4 + wid;
  int nn = min(node, N-1);
  int lane = threadIdx.x & 63;
  int h = lane >> 3, e = lane & 7;
  int begin = off[nn], deg = off[nn+1] - begin;

  float xrf[16], aw[16];
  {
    const __bf16* xp = H1 + (size_t)nn*256 + 128 + h*16;
    bf16x8 r0 = *reinterpret_cast<const bf16x8*>(xp);
    bf16x8 r1 = *reinterpret_cast<const bf16x8*>(xp + 8);
    #pragma unroll
    for (int j=0;j<8;j++){ xrf[j] = (float)r0[j]; xrf[8+j] = (float)r1[j]; }
    #pragma unroll
    for (int q=0;q<4;q++){
      float4 a4 = reinterpret_cast<const float4*>(att1 + h*16)[q];
      aw[q*4+0]=a4.x; aw[q*4+1]=a4.y; aw[q*4+2]=a4.z; aw[q*4+3]=a4.w;
    }
  }

  f32x4 acc[4];
  #pragma unroll
  for (int q=0;q<4;q++) acc[q] = (f32x4){0.f,0.f,0.f,0.f};
  float s_p = 0.f, m_run = -INFINITY;

  int nbt = (deg + 31) >> 5;
  for (int bt=0; bt<nbt; bt++){
    int kb = bt*32 + e;
    int kk[4], sidx[4];
    #pragma unroll
    for (int c=0;c<4;c++){
      kk[c] = kb + c*8;
      int kc = min(kk[c], deg-1);
      int eidx = adj[begin + kc];
      sidx[c] = (eidx < E) ? esrc[eidx] : (eidx - E);
    }
    bf16x8 v0[4], v1[4];
    #pragma unroll
    for (int c=0;c<4;c++){
      const __bf16* xp = H1 + (size_t)sidx[c]*256 + h*16;
      v0[c] = *reinterpret_cast<const bf16x8*>(xp);
      v1[c] = *reinterpret_cast<const bf16x8*>(xp + 8);
    }
    float p[4];
    #pragma unroll
    for (int c=0;c<4;c++){
      float pp = 0.f;
      #pragma unroll
      for (int j=0;j<8;j++){
        pp = fmaf(aw[j],   lrelu((float)v0[c][j] + xrf[j]),   pp);
        pp = fmaf(aw[j+8], lrelu((float)v1[c][j] + xrf[j+8]), pp);
      }
      p[c] = (kk[c] < deg) ? pp : -INFINITY;
    }
    float mc = fmaxf(fmaxf(p[0],p[1]), fmaxf(p[2],p[3]));
    mc = fmaxf(mc, __shfl_xor(mc,1,64));
    mc = fmaxf(mc, __shfl_xor(mc,2,64));
    mc = fmaxf(mc, __shfl_xor(mc,4,64));
    float mnew = fmaxf(m_run, mc);
    float cc = __expf(m_run - mnew);      // first batch: exp(-inf)=0
    m_run = mnew;
    float w[4];
    #pragma unroll
    for (int c=0;c<4;c++) w[c] = __expf(p[c] - mnew);   // invalid -> exp(-inf)=0
    s_p = s_p*cc + ((w[0]+w[1]) + (w[2]+w[3]));
    #pragma unroll
    for (int j=0;j<16;j++){
      float x0 = (j<8) ? (float)v0[0][j&7] : (float)v1[0][j&7];
      float x1 = (j<8) ? (float)v0[1][j&7] : (float)v1[1][j&7];
      float x2 = (j<8) ? (float)v0[2][j&7] : (float)v1[2][j&7];
      float x3 = (j<8) ? (float)v0[3][j&7] : (float)v1[3][j&7];
      float t = acc[j>>2][j&3]*cc;
      t = fmaf(w[0], x0, t);
      t = fmaf(w[1], x1, t);
      t = fmaf(w[2], x2, t);
      t = fmaf(w[3], x3, t);
      acc[j>>2][j&3] = t;
    }
  }
  // butterfly sum over the 8 edge-lanes (per head)
  #pragma unroll
  for (int mm=1;mm<8;mm<<=1){
    #pragma unroll
    for (int j=0;j<16;j++){
      float t = __shfl_xor(acc[j>>2][j&3], mm, 64);
      acc[j>>2][j&3] += t;
    }
    s_p += __shfl_xor(s_p, mm, 64);
  }
  if (e == 0){
    #pragma unroll
    for (int q=0;q<4;q++)
      *reinterpret_cast<f32x4*>(&obuf[wid][h*16 + q*4]) = acc[q];
  }
  float inv = 1.f/(s_p + 1e-16f);
  float2 ob = *reinterpret_cast<const float2*>(&obuf[wid][lane*2]);
  float2 bb = *reinterpret_cast<const float2*>(b1 + lane*2);
  float o0 = ob.x*inv + bb.x;
  float o1 = ob.y*inv + bb.y;
  o0 = o0 > 0.f ? o0 : expm1f(o0);
  o1 = o1 > 0.f ? o1 : expm1f(o1);
  union { __bf16 h2[2]; uint u; } pk;
  pk.h2[0] = (__bf16)o0; pk.h2[1] = (__bf16)o1;
  if (node < N)
    *reinterpret_cast<uint*>(out1 + (size_t)node*128 + lane*2) = pk.u;
}

// ---------------- layer 2 fused v4: 1 wave/node, 64-edge batched gather ------
// lane = q*16 + e. Batch = 4 chunks of 16 edges = 64 edges: deg<=64 (typical)
// is a single batch -> zero online rescales, one softmax reduction total.
__global__ __launch_bounds__(256) void k_fused2(
    const int* __restrict__ off, const int* __restrict__ adj,
    const int* __restrict__ esrc, int E, int N,
    const __bf16* __restrict__ H2, const float* __restrict__ att2,
    const float* __restrict__ b2, float* __restrict__ out)
{
  __shared__ float obuf[4][64];
  int wid = threadIdx.x >> 6;
  int node = blockIdx.x*4 + wid;
  int nn = min(node, N-1);
  int lane = threadIdx.x & 63;
  int q = lane >> 4, e = lane & 15;
  int begin = off[nn], deg = off[nn+1] - begin;

  float xrf[16], aw[16];
  {
    const __bf16* xp = H2 + (size_t)nn*128 + 64 + q*16;
    bf16x8 r0 = *reinterpret_cast<const bf16x8*>(xp);
    bf16x8 r1 = *reinterpret_cast<const bf16x8*>(xp + 8);
    #pragma unroll
    for (int j=0;j<8;j++){ xrf[j] = (float)r0[j]; xrf[8+j] = (float)r1[j]; }
    #pragma unroll
    for (int p4=0;p4<4;p4++){
      float4 a4 = reinterpret_cast<const float4*>(att2 + q*16)[p4];
      aw[p4*4+0]=a4.x; aw[p4*4+1]=a4.y; aw[p4*4+2]=a4.z; aw[p4*4+3]=a4.w;
    }
  }

  f32x4 acc[4];
  #pragma unroll
  for (int p4=0;p4<4;p4++) acc[p4] = (f32x4){0.f,0.f,0.f,0.f};
  float s_p = 0.f, m_run = -INFINITY;

  int nbt = (deg + 63) >> 6;
  for (int bt=0; bt<nbt; bt++){
    int kb = bt*64 + e;
    int kk[4], sidx[4];
    #pragma unroll
    for (int c=0;c<4;c++){
      kk[c] = kb + c*16;
      int kc = min(kk[c], deg-1);
      int eidx = adj[begin + kc];
      sidx[c] = (eidx < E) ? esrc[eidx] : (eidx - E);
    }
    bf16x8 v0[4], v1[4];
    #pragma unroll
    for (int c=0;c<4;c++){
      const __bf16* xp = H2 + (size_t)sidx[c]*128 + q*16;
      v0[c] = *reinterpret_cast<const bf16x8*>(xp);
      v1[c] = *reinterpret_cast<const bf16x8*>(xp + 8);
    }
    float p[4];
    #pragma unroll
    for (int c=0;c<4;c++){
      float pp = 0.f;
      #pragma unroll
      for (int j=0;j<8;j++){
        pp = fmaf(aw[j],   lrelu((float)v0[c][j] + xrf[j]),   pp);
        pp = fmaf(aw[j+8], lrelu((float)v1[c][j] + xrf[j+8]), pp);
      }
      pp += __shfl_xor(pp,16,64);
      pp += __shfl_xor(pp,32,64);
      p[c] = (kk[c] < deg) ? pp : -INFINITY;
    }
    float mc = fmaxf(fmaxf(p[0],p[1]), fmaxf(p[2],p[3]));
    mc = fmaxf(mc, __shfl_xor(mc,1,64));
    mc = fmaxf(mc, __shfl_xor(mc,2,64));
    mc = fmaxf(mc, __shfl_xor(mc,4,64));
    mc = fmaxf(mc, __shfl_xor(mc,8,64));
    float mnew = fmaxf(m_run, mc);
    float cc = __expf(m_run - mnew);
    m_run = mnew;
    float w[4];
    #pragma unroll
    for (int c=0;c<4;c++) w[c] = __expf(p[c] - mnew);
    s_p = s_p*cc + ((w[0]+w[1]) + (w[2]+w[3]));
    #pragma unroll
    for (int j=0;j<16;j++){
      float x0 = (j<8) ? (float)v0[0][j&7] : (float)v1[0][j&7];
      float x1 = (j<8) ? (float)v0[1][j&7] : (float)v1[1][j&7];
      float x2 = (j<8) ? (float)v0[2][j&7] : (float)v1[2][j&7];
      float x3 = (j<8) ? (float)v0[3][j&7] : (float)v1[3][j&7];
      float t = acc[j>>2][j&3]*cc;
      t = fmaf(w[0], x0, t);
      t = fmaf(w[1], x1, t);
      t = fmaf(w[2], x2, t);
      t = fmaf(w[3], x3, t);
      acc[j>>2][j&3] = t;
    }
  }
  #pragma unroll
  for (int mm=1;mm<16;mm<<=1){
    #pragma unroll
    for (int j=0;j<16;j++){
      float t = __shfl_xor(acc[j>>2][j&3], mm, 64);
      acc[j>>2][j&3] += t;
    }
    s_p += __shfl_xor(s_p, mm, 64);
  }
  if (e == 0){
    #pragma unroll
    for (int p4=0;p4<4;p4++)
      *reinterpret_cast<f32x4*>(&obuf[wid][q*16 + p4*4]) = acc[p4];
  }
  float inv = 1.f/(s_p + 1e-16f);
  float o = obuf[wid][lane]*inv + b2[lane];
  float mx = o;
  #pragma unroll
  for (int mm=1;mm<64;mm<<=1) mx = fmaxf(mx, __shfl_xor(mx,mm,64));
  float se = __expf(o - mx);
  #pragma unroll
  for (int mm=1;mm<64;mm<<=1) se += __shfl_xor(se,mm,64);
  if (node < N)
    out[(size_t)node*64 + lane] = o - mx - __logf(se);
}

extern "C" void kernel_launch(void* const* d_in, const int* in_sizes, int n_in,
                              void* d_out, int out_size, void* d_ws, size_t ws_size,
                              hipStream_t stream)
{
  const float* x    = (const float*)d_in[0];
  const int*   ei   = (const int*)  d_in[1];
  const float* Wl1  = (const float*)d_in[2];
  const float* Wr1  = (const float*)d_in[3];
  const float* att1 = (const float*)d_in[4];
  const float* b1   = (const float*)d_in[5];
  const float* Wl2  = (const float*)d_in[6];
  const float* Wr2  = (const float*)d_in[7];
  const float* att2 = (const float*)d_in[8];
  const float* b2   = (const float*)d_in[9];
  float* out = (float*)d_out;

  const int DIN = 512;
  int N  = in_sizes[0] / DIN;     // 50000
  int E  = in_sizes[1] / 2;       // 800000
  int ET = E + N;                 // + self loops
  const int* esrc = ei;
  const int* edst = ei + E;

  char* p = (char*)d_ws;
  auto walloc = [&](size_t bytes)->void*{
    void* r = (void*)p; p += (bytes + 255) & ~(size_t)255; return r;
  };
  __bf16* xb   = (__bf16*)walloc((size_t)N*DIN*2);
  __bf16* Wt1  = (__bf16*)walloc((size_t)256*512*2);
  __bf16* Wt2  = (__bf16*)walloc((size_t)128*128*2);
  __bf16* H1   = (__bf16*)walloc((size_t)N*256*2);  // [xl1 | xr1]
  __bf16* out1 = (__bf16*)walloc((size_t)N*128*2);
  __bf16* H2   = (__bf16*)walloc((size_t)N*128*2);  // [xl2 | xr2]
  int* off    = (int*)walloc((size_t)(N+1)*4);
  int* cursor = (int*)walloc((size_t)N*4);
  int* adj    = (int*)walloc((size_t)ET*4);
  int* bsum   = (int*)walloc((size_t)256*4);

  // CSR build (hierarchical scan)
  int NB = CDIV(N,256);
  hipMemsetAsync(off, 0, (size_t)(N+1)*4, stream);
  k_count_deg<<<CDIV(ET,256),256,0,stream>>>(edst, E, ET, off);
  k_scan_a<<<NB,256,0,stream>>>(off+1, N, bsum);
  k_scan_b<<<1,256,0,stream>>>(bsum, NB);
  k_scan_c<<<NB,256,0,stream>>>(off, cursor, bsum, N);
  k_fill<<<CDIV(ET,256),256,0,stream>>>(edst, E, ET, cursor, adj);

  // prep
  int n4 = N*DIN/4;
  k_cvt_bf16<<<CDIV(n4,256),256,0,stream>>>(x, xb, n4);
  k_prep_wt<<<256,512,0,stream>>>(Wl1, Wr1, Wt1, 512, 128);
  k_prep_wt<<<128,128,0,stream>>>(Wl2, Wr2, Wt2, 128, 64);

  // Layer 1: H1[N,256] = xb[N,512] @ Wt1[256,512]^T
  dim3 g1(CDIV(N,128), 2);
  gemm_mfma<<<g1,256,0,stream>>>(xb, N, 512, Wt1, 256, H1);
  k_fused1<<<CDIV(N,4),256,0,stream>>>(off, adj, esrc, E, N, H1, att1, b1, out1);

  // Layer 2: H2[N,128] = out1[N,128] @ Wt2[128,128]^T
  dim3 g2(CDIV(N,128), 1);
  gemm_mfma<<<g2,256,0,stream>>>(out1, N, 128, Wt2, 128, H2);
  k_fused2<<<CDIV(N,4),256,0,stream>>>(off, adj, esrc, E, N, H2, att2, b2, out);
}